// Round 8
// baseline (156.927 us; speedup 1.0000x reference)
//
#include <hip/hip_runtime.h>

// TopicRouter: logits = h @ gate_w^T + gate_b ; top-2 ; softmax over top-2.
// Outputs flat in d_out (float32): [0, 2B)   = topk indices as floats
//                                  [2B, 4B)  = softmax weights
//
// R8 = R7 (f32 hot path + rare f64 repair; 121.8 us) + TWO-TOKEN INTERLEAVE.
// R7 diagnosis: ~2x above the ~60 us memory floor; per-token serial chain
// (FMA -> 6 dependent shuffle levels -> gather -> top-3 -> expf) exposed at
// ~3 waves/SIMD occupancy. Fix: process tokens tA=t, tB=t+n_waves per
// iteration -- two independent chains interleave in program order, halving
// exposed latency per token; wf reads shared. VGPR ~216 (<256).
// f64 repair (TAU=1e-4) when f32 top-3 gaps are ambiguous: one top-2 rank
// flip vs the f64 np ref fails the 0.14 idx threshold; f32 path error ~3e-6.

#define B_TOKENS 131072
#define DM 768
#define NE 8
#define TAU 1e-4f

__global__ __launch_bounds__(256) void topic_router_kernel(
    const float* __restrict__ h,     // [B, 768]
    const float* __restrict__ gw,    // [8, 768]
    const float* __restrict__ gb,    // [8]
    float* __restrict__ out)         // [2B idx floats][2B weight floats]
{
    const int lane = threadIdx.x & 63;
    const int wid = (blockIdx.x * blockDim.x + threadIdx.x) >> 6;
    const int n_waves = (gridDim.x * blockDim.x) >> 6;   // 8192

    // Cache gate_w fragments: wf[e][g][j] = gw[e][g*256 + lane*4 + j]
    float wf[NE][3][4];
#pragma unroll
    for (int e = 0; e < NE; ++e)
#pragma unroll
        for (int g = 0; g < 3; ++g) {
            const float4 v = *reinterpret_cast<const float4*>(
                &gw[e * DM + g * 256 + lane * 4]);
            wf[e][g][0] = v.x; wf[e][g][1] = v.y;
            wf[e][g][2] = v.z; wf[e][g][3] = v.w;
        }

    float biasf[NE];
#pragma unroll
    for (int e = 0; e < NE; ++e) biasf[e] = gb[e];

    const bool hi32 = (lane & 32) != 0;
    const bool hi16 = (lane & 16) != 0;
    const bool hi8  = (lane & 8)  != 0;

    // ---- helpers as lambdas (inlined) ----
    auto loadrow = [&](int t, float4* dst) {
        const float* hr = h + (size_t)t * DM;
#pragma unroll
        for (int g = 0; g < 3; ++g)
            dst[g] = *reinterpret_cast<const float4*>(&hr[g * 256 + lane * 4]);
    };

    // f32 butterfly + gather: input acc[8] partials, output lg[8] full logits
    auto reduce_f32 = [&](const float* accf, float* lg) {
        float r4[4];
#pragma unroll
        for (int j = 0; j < 4; ++j) {
            const float give = hi32 ? accf[j] : accf[4 + j];
            const float keep = hi32 ? accf[4 + j] : accf[j];
            r4[j] = keep + __shfl_xor(give, 32);
        }
        float r2[2];
#pragma unroll
        for (int j = 0; j < 2; ++j) {
            const float give = hi16 ? r4[j] : r4[2 + j];
            const float keep = hi16 ? r4[2 + j] : r4[j];
            r2[j] = keep + __shfl_xor(give, 16);
        }
        const float give = hi8 ? r2[0] : r2[1];
        const float keep = hi8 ? r2[1] : r2[0];
        float v = keep + __shfl_xor(give, 8);
        v += __shfl_xor(v, 4);
        v += __shfl_xor(v, 2);
        v += __shfl_xor(v, 1);
#pragma unroll
        for (int e = 0; e < NE; ++e)
            lg[e] = __shfl(v, (e << 3) | (lane & 7)) + biasf[e];
    };

    // f64 repair: recompute token's logits in f64 from its register row
    auto repair_f64 = [&](const float4* buf, int& i0, int& i1, float& diff) {
        double acc[NE] = {0, 0, 0, 0, 0, 0, 0, 0};
#pragma unroll
        for (int g = 0; g < 3; ++g) {
            const float* bp = reinterpret_cast<const float*>(&buf[g]);
#pragma unroll
            for (int j = 0; j < 4; ++j) {
                const double hd = (double)bp[j];
#pragma unroll
                for (int e = 0; e < NE; ++e)
                    acc[e] = fma(hd, (double)wf[e][g][j], acc[e]);
            }
        }
        double d4[4];
#pragma unroll
        for (int j = 0; j < 4; ++j) {
            const double give = hi32 ? acc[j] : acc[4 + j];
            const double keep = hi32 ? acc[4 + j] : acc[j];
            d4[j] = keep + __shfl_xor(give, 32);
        }
        double d2[2];
#pragma unroll
        for (int j = 0; j < 2; ++j) {
            const double give = hi16 ? d4[j] : d4[2 + j];
            const double keep = hi16 ? d4[2 + j] : d4[j];
            d2[j] = keep + __shfl_xor(give, 16);
        }
        const double give = hi8 ? d2[0] : d2[1];
        const double keep = hi8 ? d2[1] : d2[0];
        double dv = keep + __shfl_xor(give, 8);
        dv += __shfl_xor(dv, 4);
        dv += __shfl_xor(dv, 2);
        dv += __shfl_xor(dv, 1);
        double dlg[NE];
#pragma unroll
        for (int e = 0; e < NE; ++e)
            dlg[e] = __shfl(dv, (e << 3) | (lane & 7)) + (double)biasf[e];
        i0 = 0; double dv0 = dlg[0];
#pragma unroll
        for (int e = 1; e < NE; ++e)
            if (dlg[e] > dv0) { dv0 = dlg[e]; i0 = e; }
        i1 = (i0 == 0) ? 1 : 0; double dv1 = dlg[i1];
#pragma unroll
        for (int e = 0; e < NE; ++e)
            if (e != i0 && dlg[e] > dv1) { dv1 = dlg[e]; i1 = e; }
        diff = (float)(dv1 - dv0);
    };

    auto emit = [&](int t, int i0, int i1, float diff) {
        const float ex = expf(diff);              // diff <= 0
        const float w1 = ex / (1.0f + ex);
        const float w0 = 1.0f - w1;
        if (lane == 0) {
            *reinterpret_cast<float2*>(&out[2 * (size_t)t]) =
                make_float2((float)i0, (float)i1);
            *reinterpret_cast<float2*>(
                &out[2 * (size_t)B_TOKENS + 2 * (size_t)t]) =
                make_float2(w0, w1);
        }
    };

    // ---- pair pipeline: tokens (tA, tB=tA+n_waves), stride 2*n_waves ----
    float4 bufA[3], bufB[3];
    if (wid < B_TOKENS) loadrow(wid, bufA);
    if (wid + n_waves < B_TOKENS) loadrow(wid + n_waves, bufB);

    for (int tA = wid; tA < B_TOKENS; tA += 2 * n_waves) {
        const int tB = tA + n_waves;
        const bool hasB = (tB < B_TOKENS);

        // prefetch next pair
        float4 nbufA[3], nbufB[3];
        const int tnA = tA + 2 * n_waves;
        if (tnA < B_TOKENS) {
            loadrow(tnA, nbufA);
            if (tnA + n_waves < B_TOKENS) loadrow(tnA + n_waves, nbufB);
        }

        // ---- interleaved f32 dots: two independent chains share wf ----
        float accA[NE] = {0, 0, 0, 0, 0, 0, 0, 0};
        float accB[NE] = {0, 0, 0, 0, 0, 0, 0, 0};
#pragma unroll
        for (int g = 0; g < 3; ++g) {
            const float* ap = reinterpret_cast<const float*>(&bufA[g]);
            const float* bp = reinterpret_cast<const float*>(&bufB[g]);
#pragma unroll
            for (int j = 0; j < 4; ++j) {
                const float ha = ap[j];
                const float hb = bp[j];
#pragma unroll
                for (int e = 0; e < NE; ++e) {
                    accA[e] = fmaf(ha, wf[e][g][j], accA[e]);
                    accB[e] = fmaf(hb, wf[e][g][j], accB[e]);
                }
            }
        }

        // ---- interleaved butterflies + gathers ----
        float lgA[NE], lgB[NE];
        reduce_f32(accA, lgA);
        reduce_f32(accB, lgB);

        // ---- top-3 + ambiguity test + emit, token A ----
        {
            int i0 = 0; float v0 = lgA[0];
#pragma unroll
            for (int e = 1; e < NE; ++e)
                if (lgA[e] > v0) { v0 = lgA[e]; i0 = e; }
            int i1 = -1; float v1 = -3.4e38f;
#pragma unroll
            for (int e = 0; e < NE; ++e)
                if (e != i0 && lgA[e] > v1) { v1 = lgA[e]; i1 = e; }
            float v2 = -3.4e38f;
#pragma unroll
            for (int e = 0; e < NE; ++e)
                if (e != i0 && e != i1 && lgA[e] > v2) v2 = lgA[e];
            float diff = v1 - v0;
            if (__builtin_expect((v0 - v1 < TAU) || (v1 - v2 < TAU), 0))
                repair_f64(bufA, i0, i1, diff);
            emit(tA, i0, i1, diff);
        }

        // ---- token B ----
        if (hasB) {
            int i0 = 0; float v0 = lgB[0];
#pragma unroll
            for (int e = 1; e < NE; ++e)
                if (lgB[e] > v0) { v0 = lgB[e]; i0 = e; }
            int i1 = -1; float v1 = -3.4e38f;
#pragma unroll
            for (int e = 0; e < NE; ++e)
                if (e != i0 && lgB[e] > v1) { v1 = lgB[e]; i1 = e; }
            float v2 = -3.4e38f;
#pragma unroll
            for (int e = 0; e < NE; ++e)
                if (e != i0 && e != i1 && lgB[e] > v2) v2 = lgB[e];
            float diff = v1 - v0;
            if (__builtin_expect((v0 - v1 < TAU) || (v1 - v2 < TAU), 0))
                repair_f64(bufB, i0, i1, diff);
            emit(tB, i0, i1, diff);
        }

        // rotate prefetch
#pragma unroll
        for (int g = 0; g < 3; ++g) { bufA[g] = nbufA[g]; bufB[g] = nbufB[g]; }
    }
}

extern "C" void kernel_launch(void* const* d_in, const int* in_sizes, int n_in,
                              void* d_out, int out_size, void* d_ws, size_t ws_size,
                              hipStream_t stream) {
    const float* h  = (const float*)d_in[0];
    const float* gw = (const float*)d_in[1];
    const float* gb = (const float*)d_in[2];
    float* out = (float*)d_out;

    dim3 grid(2048), block(256);
    topic_router_kernel<<<grid, block, 0, stream>>>(h, gw, gb, out);
}

// Round 9
// 103.946 us; speedup vs baseline: 1.5097x; 1.5097x over previous
//
#include <hip/hip_runtime.h>

// TopicRouter: logits = h @ gate_w^T + gate_b ; top-2 ; softmax over top-2.
// Outputs flat in d_out (float32): [0, 2B)   = topk indices as floats
//                                  [2B, 4B)  = softmax weights
//
// R9: split repair into a second kernel to buy the 4th wave/SIMD.
// History: R7 (f32 + inline f64 repair) = 121.8 us at ~170 VGPR (3 waves/
// SIMD). R8 (two-token ILP) = 157 us (VGPR ~230 -> 2 waves/SIMD): ILP and
// TLP trade against the same RF; TLP wins here. R9 removes the two >128-VGPR
// offenders from the hot kernel: (a) the inline f64 repair path (16+ regs of
// cold live range) -> kernel2; (b) the prefetch buffer (-12) -> 4-wave TLP
// covers the ~900cyc miss (4 x ~450 compute cyc > 900).
// kernel1: f32 dot + split-butterfly (18 DS b32/token) + top-3; writes
//   idx/weights AND a flag byte (always written -> no reset, no stale state).
//   Ambiguous = min(gap12, gap23) < TAU=1e-4 (f32 path error ~3e-6, 30x
//   margin; one top-2 rank flip vs f64 np ref fails the 0.14 idx threshold).
// kernel2: 1 wave per 64 tokens; ballot on flags; early-exit if clean;
//   wave-cooperative f64 recompute for flagged tokens (~1e-3 rate).

#define B_TOKENS 131072
#define DM 768
#define NE 8
#define TAU 1e-4f

__global__ __launch_bounds__(256) void router_main(
    const float* __restrict__ h,     // [B, 768]
    const float* __restrict__ gw,    // [8, 768]
    const float* __restrict__ gb,    // [8]
    float* __restrict__ out,         // [2B idx floats][2B weight floats]
    unsigned char* __restrict__ flags)
{
    const int lane = threadIdx.x & 63;
    const int wid = (blockIdx.x * blockDim.x + threadIdx.x) >> 6;
    const int n_waves = (gridDim.x * blockDim.x) >> 6;

    // Cache gate_w fragments: wf[e][g][j] = gw[e][g*256 + lane*4 + j]
    float wf[NE][3][4];
#pragma unroll
    for (int e = 0; e < NE; ++e)
#pragma unroll
        for (int g = 0; g < 3; ++g) {
            const float4 v = *reinterpret_cast<const float4*>(
                &gw[e * DM + g * 256 + lane * 4]);
            wf[e][g][0] = v.x; wf[e][g][1] = v.y;
            wf[e][g][2] = v.z; wf[e][g][3] = v.w;
        }

    float biasf[NE];   // uniform loads -> SGPRs
#pragma unroll
    for (int e = 0; e < NE; ++e) biasf[e] = gb[e];

    const bool hi32 = (lane & 32) != 0;
    const bool hi16 = (lane & 16) != 0;
    const bool hi8  = (lane & 8)  != 0;

    for (int t = wid; t < B_TOKENS; t += n_waves) {
        const float* hr = h + (size_t)t * DM;
        float4 buf[3];
#pragma unroll
        for (int g = 0; g < 3; ++g)
            buf[g] = *reinterpret_cast<const float4*>(&hr[g * 256 + lane * 4]);

        // ---- f32 partial dot: 96 FMAs/lane ----
        float accf[NE] = {0, 0, 0, 0, 0, 0, 0, 0};
#pragma unroll
        for (int g = 0; g < 3; ++g) {
            const float* bp = reinterpret_cast<const float*>(&buf[g]);
#pragma unroll
            for (int j = 0; j < 4; ++j) {
                const float hv = bp[j];
#pragma unroll
                for (int e = 0; e < NE; ++e)
                    accf[e] = fmaf(hv, wf[e][g][j], accf[e]);
            }
        }

        // ---- f32 split-butterfly reduce (18 b32 DS ops) ----
        float r4[4];
#pragma unroll
        for (int j = 0; j < 4; ++j) {
            const float give = hi32 ? accf[j] : accf[4 + j];
            const float keep = hi32 ? accf[4 + j] : accf[j];
            r4[j] = keep + __shfl_xor(give, 32);
        }
        float r2[2];
#pragma unroll
        for (int j = 0; j < 2; ++j) {
            const float give = hi16 ? r4[j] : r4[2 + j];
            const float keep = hi16 ? r4[2 + j] : r4[j];
            r2[j] = keep + __shfl_xor(give, 16);
        }
        const float give = hi8 ? r2[0] : r2[1];
        const float keep = hi8 ? r2[1] : r2[0];
        float v = keep + __shfl_xor(give, 8);
        v += __shfl_xor(v, 4);
        v += __shfl_xor(v, 2);
        v += __shfl_xor(v, 1);

        // gather all 8 logits into every lane (identical in all lanes)
        float lg[NE];
#pragma unroll
        for (int e = 0; e < NE; ++e)
            lg[e] = __shfl(v, (e << 3) | (lane & 7)) + biasf[e];

        // ---- f32 top-3 (lax.top_k tie-break: lower index wins) ----
        int i0 = 0; float v0 = lg[0];
#pragma unroll
        for (int e = 1; e < NE; ++e)
            if (lg[e] > v0) { v0 = lg[e]; i0 = e; }
        int i1 = -1; float v1 = -3.4e38f;
#pragma unroll
        for (int e = 0; e < NE; ++e)
            if (e != i0 && lg[e] > v1) { v1 = lg[e]; i1 = e; }
        float v2 = -3.4e38f;
#pragma unroll
        for (int e = 0; e < NE; ++e)
            if (e != i0 && e != i1 && lg[e] > v2) v2 = lg[e];

        const bool amb = (v0 - v1 < TAU) || (v1 - v2 < TAU);

        // softmax over top-2 (diff = logit1 - logit0 <= 0)
        const float ex = expf(v1 - v0);
        const float w1 = ex / (1.0f + ex);
        const float w0 = 1.0f - w1;

        if (lane == 0) {
            *reinterpret_cast<float2*>(&out[2 * (size_t)t]) =
                make_float2((float)i0, (float)i1);
            *reinterpret_cast<float2*>(
                &out[2 * (size_t)B_TOKENS + 2 * (size_t)t]) =
                make_float2(w0, w1);
            flags[t] = amb ? 1 : 0;     // ALWAYS written -> deterministic
        }
    }
}

// One wave per 64 consecutive tokens; early-exit when no flags set.
__global__ __launch_bounds__(256) void router_repair(
    const float* __restrict__ h,
    const float* __restrict__ gw,
    const float* __restrict__ gb,
    float* __restrict__ out,
    const unsigned char* __restrict__ flags)
{
    const int lane = threadIdx.x & 63;
    const int w = (blockIdx.x * blockDim.x + threadIdx.x) >> 6;
    const int t0 = w * 64;
    if (t0 >= B_TOKENS) return;

    const unsigned char f = flags[t0 + lane];
    unsigned long long mask = __ballot(f != 0);
    if (mask == 0ull) return;            // common case: ~2-3 us total scan

    // cold path: load weights, then repair each flagged token in f64
    float wf[NE][3][4];
#pragma unroll
    for (int e = 0; e < NE; ++e)
#pragma unroll
        for (int g = 0; g < 3; ++g) {
            const float4 vv = *reinterpret_cast<const float4*>(
                &gw[e * DM + g * 256 + lane * 4]);
            wf[e][g][0] = vv.x; wf[e][g][1] = vv.y;
            wf[e][g][2] = vv.z; wf[e][g][3] = vv.w;
        }
    double biasd[NE];
#pragma unroll
    for (int e = 0; e < NE; ++e) biasd[e] = (double)gb[e];

    const bool hi32 = (lane & 32) != 0;
    const bool hi16 = (lane & 16) != 0;
    const bool hi8  = (lane & 8)  != 0;

    while (mask) {
        const int p = __ffsll(mask) - 1;
        mask &= (mask - 1);
        const int t = t0 + p;

        const float* hr = h + (size_t)t * DM;
        float4 buf[3];
#pragma unroll
        for (int g = 0; g < 3; ++g)
            buf[g] = *reinterpret_cast<const float4*>(&hr[g * 256 + lane * 4]);

        double acc[NE] = {0, 0, 0, 0, 0, 0, 0, 0};
#pragma unroll
        for (int g = 0; g < 3; ++g) {
            const float* bp = reinterpret_cast<const float*>(&buf[g]);
#pragma unroll
            for (int j = 0; j < 4; ++j) {
                const double hd = (double)bp[j];
#pragma unroll
                for (int e = 0; e < NE; ++e)
                    acc[e] = fma(hd, (double)wf[e][g][j], acc[e]);
            }
        }
        double d4[4];
#pragma unroll
        for (int j = 0; j < 4; ++j) {
            const double give = hi32 ? acc[j] : acc[4 + j];
            const double keep = hi32 ? acc[4 + j] : acc[j];
            d4[j] = keep + __shfl_xor(give, 32);
        }
        double d2[2];
#pragma unroll
        for (int j = 0; j < 2; ++j) {
            const double give = hi16 ? d4[j] : d4[2 + j];
            const double keep = hi16 ? d4[2 + j] : d4[j];
            d2[j] = keep + __shfl_xor(give, 16);
        }
        const double give = hi8 ? d2[0] : d2[1];
        const double keep = hi8 ? d2[1] : d2[0];
        double dv = keep + __shfl_xor(give, 8);
        dv += __shfl_xor(dv, 4);
        dv += __shfl_xor(dv, 2);
        dv += __shfl_xor(dv, 1);

        double dlg[NE];
#pragma unroll
        for (int e = 0; e < NE; ++e)
            dlg[e] = __shfl(dv, (e << 3) | (lane & 7)) + biasd[e];

        int i0 = 0; double dv0 = dlg[0];
#pragma unroll
        for (int e = 1; e < NE; ++e)
            if (dlg[e] > dv0) { dv0 = dlg[e]; i0 = e; }
        int i1 = (i0 == 0) ? 1 : 0; double dv1 = dlg[i1];
#pragma unroll
        for (int e = 0; e < NE; ++e)
            if (e != i0 && dlg[e] > dv1) { dv1 = dlg[e]; i1 = e; }

        const float ex = expf((float)(dv1 - dv0));
        const float w1 = ex / (1.0f + ex);
        const float w0 = 1.0f - w1;

        if (lane == 0) {
            *reinterpret_cast<float2*>(&out[2 * (size_t)t]) =
                make_float2((float)i0, (float)i1);
            *reinterpret_cast<float2*>(
                &out[2 * (size_t)B_TOKENS + 2 * (size_t)t]) =
                make_float2(w0, w1);
        }
    }
}

extern "C" void kernel_launch(void* const* d_in, const int* in_sizes, int n_in,
                              void* d_out, int out_size, void* d_ws, size_t ws_size,
                              hipStream_t stream) {
    const float* h  = (const float*)d_in[0];
    const float* gw = (const float*)d_in[1];
    const float* gb = (const float*)d_in[2];
    float* out = (float*)d_out;
    unsigned char* flags = (unsigned char*)d_ws;   // B_TOKENS bytes

    router_main<<<dim3(2048), dim3(256), 0, stream>>>(h, gw, gb, out, flags);
    router_repair<<<dim3(512), dim3(256), 0, stream>>>(h, gw, gb, out, flags);
}